// Round 1
// baseline (1521.117 us; speedup 1.0000x reference)
//
#include <hip/hip_runtime.h>
#include <hip/hip_bf16.h>

#define Bc 4
#define Tc 256
#define Nc 4096
#define Kc 64
#define DEGc 4
#define Lc (Tc - 1)
#define NNZc (Bc * Nc * DEGc)
#define NPB 16                       // blocks per batch
#define TPB 256
#define NODES_PER (Nc / NPB)         // 256 -> one node per thread
#define EDGES_PER ((Nc * DEGc) / NPB) // 1024 -> 4 edges per thread
#define LOG_N 8.31776616671934f

__device__ __forceinline__ float cohLoadF(float* p) {
  return __hip_atomic_load(p, __ATOMIC_RELAXED, __HIP_MEMORY_SCOPE_AGENT);
}
__device__ __forceinline__ void cohStoreF(float* p, float v) {
  __hip_atomic_store(p, v, __ATOMIC_RELAXED, __HIP_MEMORY_SCOPE_AGENT);
}

__device__ __forceinline__ float blockSum(float v, volatile float* red) {
#pragma unroll
  for (int o = 1; o < 64; o <<= 1) v += __shfl_xor(v, o, 64);
  __syncthreads();
  if ((threadIdx.x & 63) == 0) red[threadIdx.x >> 6] = v;
  __syncthreads();
  return red[0] + red[1] + red[2] + red[3];
}
__device__ __forceinline__ float blockMax(float v, volatile float* red) {
#pragma unroll
  for (int o = 1; o < 64; o <<= 1) v = fmaxf(v, __shfl_xor(v, o, 64));
  __syncthreads();
  if ((threadIdx.x & 63) == 0) red[threadIdx.x >> 6] = v;
  __syncthreads();
  return fmaxf(fmaxf(red[0], red[1]), fmaxf(red[2], red[3]));
}

// em[r][n] = log_softmax(obs[r,:] @ W)[n], one block per row r = b*T + t
__global__ __launch_bounds__(TPB) void em_kernel(const float* __restrict__ obs,
                                                 const float* __restrict__ W,
                                                 float* __restrict__ em) {
  const int r = blockIdx.x, tid = threadIdx.x;
  __shared__ float o[Kc];
  __shared__ float red[8];
  if (tid < Kc) o[tid] = obs[(size_t)r * Kc + tid];
  __syncthreads();
  float4 acc[4];
#pragma unroll
  for (int gI = 0; gI < 4; ++gI) acc[gI] = make_float4(0.f, 0.f, 0.f, 0.f);
  const float4* W4 = (const float4*)W;
  for (int k = 0; k < Kc; ++k) {
    const float ov = o[k];
    const float4* wr = W4 + (size_t)k * (Nc / 4);
#pragma unroll
    for (int gI = 0; gI < 4; ++gI) {
      float4 w = wr[gI * 256 + tid];
      acc[gI].x = fmaf(ov, w.x, acc[gI].x);
      acc[gI].y = fmaf(ov, w.y, acc[gI].y);
      acc[gI].z = fmaf(ov, w.z, acc[gI].z);
      acc[gI].w = fmaf(ov, w.w, acc[gI].w);
    }
  }
  float m = -INFINITY;
#pragma unroll
  for (int gI = 0; gI < 4; ++gI)
    m = fmaxf(m, fmaxf(fmaxf(acc[gI].x, acc[gI].y), fmaxf(acc[gI].z, acc[gI].w)));
  m = blockMax(m, red);
  float s = 0.f;
#pragma unroll
  for (int gI = 0; gI < 4; ++gI)
    s += __expf(acc[gI].x - m) + __expf(acc[gI].y - m) + __expf(acc[gI].z - m) + __expf(acc[gI].w - m);
  s = blockSum(s, red);
  const float lse = m + __logf(s);
  float4* em4 = (float4*)em;
#pragma unroll
  for (int gI = 0; gI < 4; ++gI) {
    float4 w = acc[gI];
    w.x -= lse; w.y -= lse; w.z -= lse; w.w -= lse;
    em4[(size_t)r * (Nc / 4) + gI * 256 + tid] = w;
  }
}

// Sequential scan: grid = B*NPB blocks; per-b spin barrier between steps.
// Thread tid of block (b, sl) owns node = sl*256+tid and its 4 out-edges.
__global__ __launch_bounds__(TPB) void scan_kernel(
    const int* __restrict__ duration,
    const int* __restrict__ tidx,   // (L, NNZ, 3) int32 (b, src, tgt)
    const float* __restrict__ tlv,  // (L, NNZ)
    const float* __restrict__ em,   // (B*T, N)
    float* __restrict__ sbuf,       // [2][B*N] exp-sum scatter buffers
    float* __restrict__ S,          // [T][B] per-step normalizer sums
    unsigned int* __restrict__ cnt, // [B*16] barrier counters (padded)
    float* __restrict__ out) {
  const int g = blockIdx.x;
  const int b = g / NPB, sl = g % NPB;
  const int tid = threadIdx.x;
  __shared__ float red[8];

  const int node = sl * NODES_PER + tid;                         // node within b
  const int ebase = b * (Nc * DEGc) + sl * EDGES_PER + tid * 4;  // first of 4 edges
  unsigned int* mycnt = cnt + b * 16;

  // ---- t = 0: la0 = em[b,0,:] - log N ; S[0] = sum exp(la0) ----
  float la = em[((size_t)b * Tc) * Nc + node] - LOG_N;
  {
    float tot = blockSum(__expf(la), red);
    if (tid == 0) unsafeAtomicAdd(&S[0 * Bc + b], tot);
  }

  // prefetch step-1 edges (idx row 0): 4 triplets = 3 int4, lv = 1 float4
  int4 c0, c1, c2; float4 cl;
  {
    const size_t e = (size_t)ebase;
    const int4* ip = (const int4*)tidx + ((e * 3) >> 2);
    c0 = ip[0]; c1 = ip[1]; c2 = ip[2];
    cl = ((const float4*)tlv)[e >> 2];
  }

  for (int t = 1; t <= Lc; ++t) {
    // ---- P: prefetch next step's edges + this step's emission ----
    int4 n0 = c0, n1 = c1, n2 = c2; float4 nl = cl;
    if (t < Lc) {
      const size_t e = (size_t)t * NNZc + (size_t)ebase;  // row t -> step t+1
      const int4* ip = (const int4*)tidx + ((e * 3) >> 2);
      n0 = ip[0]; n1 = ip[1]; n2 = ip[2];
      nl = ((const float4*)tlv)[e >> 2];
    }
    const float em_t = em[((size_t)b * Tc + t) * Nc + node];

    // ---- A: scatter exp(la + lv) into this step's parity buffer ----
    // tgt positions inside the 3 int4s: [0].z, [1].y, [2].x, [2].w
    float* sb = sbuf + (size_t)(t & 1) * (Bc * Nc) + (size_t)b * Nc;
    unsafeAtomicAdd(&sb[c0.z], __expf(la + cl.x));
    unsafeAtomicAdd(&sb[c1.y], __expf(la + cl.y));
    unsafeAtomicAdd(&sb[c2.x], __expf(la + cl.z));
    unsafeAtomicAdd(&sb[c2.w], __expf(la + cl.w));

    // ---- per-b grid barrier (monotone counter, 16 arrivals/step) ----
    __syncthreads();  // drains each wave's vmem (atomics complete at MALL)
    if (tid == 0) {
      __builtin_amdgcn_sched_barrier(0);
      __hip_atomic_fetch_add(mycnt, 1u, __ATOMIC_RELAXED, __HIP_MEMORY_SCOPE_AGENT);
      const unsigned target = (unsigned)NPB * (unsigned)t;
      while (__hip_atomic_load(mycnt, __ATOMIC_RELAXED, __HIP_MEMORY_SCOPE_AGENT) < target)
        __builtin_amdgcn_s_sleep(1);
      __builtin_amdgcn_sched_barrier(0);
    }
    __syncthreads();

    // ---- B: gather my node's sum, renormalize with lag-1 log S ----
    float sv = cohLoadF(&sb[node]);
    cohStoreF(&sb[node], 0.0f);  // re-zero for step t+2
    const float logSp = __logf(cohLoadF(&S[(t - 1) * Bc + b]));
    const float v = __logf(sv) + em_t;  // sv==0 -> -inf, propagates safely
    float tot = blockSum(__expf(v), red);
    if (tid == 0) unsafeAtomicAdd(&S[t * Bc + b], tot);
    la = v - logSp;

    c0 = n0; c1 = n1; c2 = n2; cl = nl;
  }

  // ---- final barrier so S[Lc] is globally complete ----
  __syncthreads();
  if (tid == 0) {
    __builtin_amdgcn_sched_barrier(0);
    __hip_atomic_fetch_add(mycnt, 1u, __ATOMIC_RELAXED, __HIP_MEMORY_SCOPE_AGENT);
    const unsigned target = (unsigned)NPB * (unsigned)Tc;
    while (__hip_atomic_load(mycnt, __ATOMIC_RELAXED, __HIP_MEMORY_SCOPE_AGENT) < target)
      __builtin_amdgcn_s_sleep(1);
    __builtin_amdgcn_sched_barrier(0);
  }
  __syncthreads();

  // out[b] = log S[t*] + sum_{tau<=t*-2} log S[tau]   (t* = duration[b]-1)
  if (sl == 0) {
    const int tstar = duration[b] - 1;
    const int tau = tid;  // T == TPB == 256
    float v = 0.0f;
    if (tau == tstar || tau <= tstar - 2)
      v = __logf(cohLoadF(&S[tau * Bc + b]));
    float tot = blockSum(v, red);
    if (tid == 0) out[b] = tot;
  }
}

extern "C" void kernel_launch(void* const* d_in, const int* in_sizes, int n_in,
                              void* d_out, int out_size, void* d_ws, size_t ws_size,
                              hipStream_t stream) {
  const float* obs = (const float*)d_in[0];
  const float* W = (const float*)d_in[1];
  const int* duration = (const int*)d_in[2];
  const int* tidx = (const int*)d_in[3];
  const float* tlv = (const float*)d_in[4];
  float* out = (float*)d_out;

  float* em = (float*)d_ws;                                // B*T*N floats (16 MB)
  float* sbuf = em + (size_t)Bc * Tc * Nc;                 // 2*B*N floats
  float* S = sbuf + (size_t)2 * Bc * Nc;                   // T*B floats
  unsigned int* cnt = (unsigned int*)(S + (size_t)Tc * Bc);// 64 uints

  const size_t zero_bytes =
      ((size_t)2 * Bc * Nc + (size_t)Tc * Bc) * sizeof(float) + 64 * sizeof(unsigned int);
  hipMemsetAsync(sbuf, 0, zero_bytes, stream);

  em_kernel<<<dim3(Bc * Tc), dim3(TPB), 0, stream>>>(obs, W, em);
  scan_kernel<<<dim3(Bc * NPB), dim3(TPB), 0, stream>>>(duration, tidx, tlv, em,
                                                        sbuf, S, cnt, out);
}